// Round 11
// baseline (700.836 us; speedup 1.0000x reference)
//
#include <hip/hip_runtime.h>
#include <hip/hip_cooperative_groups.h>

namespace cg = cooperative_groups;

#define NN 100000
#define NE 1600000
#define NT (2 * NN)        // combined nodes (sr | tg+NN)
#define ET (2 * NE)        // combined edges
#define DIM 128
#define NS 15000
#define PAD 136                 // LDS row stride in bf16
#define NRANGE 16               // dst-range partition
#define RSZ (NT / NRANGE)       // 12500 nodes/range; LDS hist = 50 KB
#define CH 16                   // sub-chunks per range
#define BCAP 210000             // per-range bucket capacity
#define NE4 (NE / 4)            // 400000
#define CGRID 256               // coop grid: 1 block/CU guaranteed resident
#define CTHR 1024

typedef __attribute__((ext_vector_type(8))) short frag_ab;  // 8 bf16
typedef __attribute__((ext_vector_type(4))) float frag_cd;  // 4 f32
typedef __attribute__((ext_vector_type(4))) int i4;
typedef __attribute__((ext_vector_type(2))) float f32x2;    // native vec for nt-store

__device__ __forceinline__ unsigned short f2bf(float f) {  // RNE
    unsigned int u = __float_as_uint(f);
    u += 0x7fff + ((u >> 16) & 1);
    return (unsigned short)(u >> 16);
}
__device__ __forceinline__ float bflo(unsigned int u) { return __uint_as_float(u << 16); }
__device__ __forceinline__ float bfhi(unsigned int u) { return __uint_as_float(u & 0xffff0000u); }

// ================= cooperative CSR build: 6 dispatches -> 1 =================
// Phases (grid.sync between cross-block deps):
//  P0 convW (independent)  P1 bucket  |  P2 hist  |  P3 cnt/dinv/bsum
//  |  P4 prefix+row_ptr+P-base  |  P5 fillp
// Geometry: 256 blocks x 1024 thr, 1 block/CU guaranteed (52 KB LDS, VGPR<=128
// via launch_bounds(1024)).  hist/fillp keep the R7-proven 256-slot geometry.
__global__ __launch_bounds__(CTHR) void csr_coop_k(
    const float* __restrict__ W0, const float* __restrict__ W1,
    unsigned short* __restrict__ wt0, unsigned short* __restrict__ wt1,
    const int* __restrict__ e_sr, const int* __restrict__ e_tg,
    int* __restrict__ gcur, int* __restrict__ bkt, int* __restrict__ P,
    int* __restrict__ cnt, float* __restrict__ dinv, int* __restrict__ bsum,
    int* __restrict__ row_ptr, int* __restrict__ csr_src)
{
    cg::grid_group grid = cg::this_grid();
    __shared__ int lds_i[RSZ];          // 50 KB, reused per phase
    __shared__ int bcnt[16][NRANGE];    // 1 KB (16 waves)
    __shared__ int bbase[16][NRANGE];   // 1 KB
    const int tid = threadIdx.x;
    const int bid = blockIdx.x;

    // ---- P0: Wt[n][k] = bf16(W[k][n]), both weights ----
    for (int i = bid * CTHR + tid; i < 2 * DIM * DIM; i += CGRID * CTHR) {
        const float* W = (i < DIM * DIM) ? W0 : W1;
        unsigned short* wt = (i < DIM * DIM) ? wt0 : wt1;
        const int ii = i & (DIM * DIM - 1);
        const int n = ii & 127, k = ii >> 7;
        wt[n * DIM + k] = f2bf(W[k * DIM + n]);
    }

    // ---- P1: bucket edges by dst-range (gcur memset-0 before launch) ----
    // packed word: (dst_local << 18) | src_global
    const int NIT = (2 * NE4 + CGRID * CTHR - 1) / (CGRID * CTHR);  // 4
    for (int it = 0; it < NIT; ++it) {
        const int g = it * (CGRID * CTHR) + bid * CTHR + tid;
        const bool val = g < 2 * NE4;
        i4 s4 = {0, 0, 0, 0}, d4 = {0, 0, 0, 0};
        if (val) {
            if (g < NE4) {
                s4 = *((const i4*)e_sr + g);
                d4 = *((const i4*)e_sr + NE4 + g);
            } else {
                s4 = *((const i4*)e_tg + g - NE4);
                d4 = *((const i4*)e_tg + g);
                s4 += NN;
                d4 += NN;
            }
        }
        const int wv = tid >> 6;
        if (tid < 16 * NRANGE) ((int*)bcnt)[tid] = 0;
        __syncthreads();
        int rr[4], lr[4];
        if (val) {
#pragma unroll
            for (int j = 0; j < 4; ++j) {
                rr[j] = d4[j] / RSZ;
                lr[j] = atomicAdd(&bcnt[wv][rr[j]], 1);
            }
        }
        __syncthreads();
        if (tid < NRANGE) {
            int tot = 0, pre[16];
#pragma unroll
            for (int w = 0; w < 16; ++w) { pre[w] = tot; tot += bcnt[w][tid]; }
            const int b = atomicAdd(&gcur[tid], tot);
#pragma unroll
            for (int w = 0; w < 16; ++w) bbase[w][tid] = b + pre[w];
        }
        __syncthreads();
        if (val) {
#pragma unroll
            for (int j = 0; j < 4; ++j) {
                const int dtl = d4[j] - rr[j] * RSZ;
                bkt[rr[j] * BCAP + bbase[wv][rr[j]] + lr[j]] = (dtl << 18) | s4[j];
            }
        }
        __syncthreads();  // protect bcnt re-zero next iter
    }
    grid.sync();

    // ---- P2: hist slot (r,c) -> P[c][node] ----
    {
        const int r = bid & (NRANGE - 1);
        const int c = bid >> 4;
        const int lo = r * RSZ;
        for (int i = tid; i < RSZ; i += CTHR) lds_i[i] = 0;
        __syncthreads();
        const int n_r = gcur[r];
        const int S = (n_r + CH - 1) / CH;
        const int s0 = c * S;
        int s1 = s0 + S; if (s1 > n_r) s1 = n_r;
        for (int v = s0 + tid; v < s1; v += CTHR) {
            const unsigned int w = (unsigned int)bkt[r * BCAP + v];
            atomicAdd(&lds_i[w >> 18], 1);
        }
        __syncthreads();
        for (int i = tid; i < RSZ; i += CTHR) P[c * NT + lo + i] = lds_i[i];
    }
    grid.sync();

    // ---- P3: cnt = sum_c P, dinv, per-block sums (1024-node blocks) ----
    {
        const int i = bid * CTHR + tid;  // CGRID*CTHR = 262144 >= NT: one pass
        int s = 0;
        if (i < NT) {
#pragma unroll
            for (int c = 0; c < CH; ++c) s += P[c * NT + i];
            cnt[i] = s;
            dinv[i] = rsqrtf((float)(s + 1));  // +1 self-loop
        }
        lds_i[tid] = s;
        __syncthreads();
        for (int off = 512; off > 0; off >>= 1) {
            if (tid < off) lds_i[tid] += lds_i[tid + off];
            __syncthreads();
        }
        if (tid == 0) bsum[bid] = lds_i[0];
    }
    grid.sync();

    // ---- P4: redundant 256-prefix + local 1024-scan -> row_ptr, P-base ----
    {
        // exclusive prefix of bsum over blocks < bid (redundant per block)
        lds_i[tid] = 0;
        __syncthreads();
        if (tid < CGRID) lds_i[tid] = bsum[tid];
        __syncthreads();
        for (int off = 1; off < CGRID; off <<= 1) {
            int add = (tid >= off && tid < CGRID) ? lds_i[tid - off] : 0;
            __syncthreads();
            if (tid < CGRID) lds_i[tid] += add;
            __syncthreads();
        }
        const int boff = (bid == 0) ? 0 : lds_i[bid - 1];
        __syncthreads();
        // local exclusive scan of this block's 1024 cnt values
        const int i = bid * CTHR + tid;
        const int v = (i < NT) ? cnt[i] : 0;
        lds_i[tid] = v;
        __syncthreads();
        for (int off = 1; off < CTHR; off <<= 1) {
            int add = (tid >= off) ? lds_i[tid - off] : 0;
            __syncthreads();
            lds_i[tid] += add;
            __syncthreads();
        }
        if (bid == 0 && tid == 0) row_ptr[NT] = ET;
        if (i < NT) {
            const int rp = boff + lds_i[tid] - v;
            row_ptr[i] = rp;
            int run = rp;
#pragma unroll
            for (int c = 0; c < CH; ++c) {
                const int pv = P[c * NT + i];
                P[c * NT + i] = run;
                run += pv;
            }
        }
    }
    grid.sync();

    // ---- P5: fillp slot (r,c): LDS cursors over dense bucket ----
    {
        const int r = bid & (NRANGE - 1);
        const int c = bid >> 4;
        const int lo = r * RSZ;
        for (int i = tid; i < RSZ; i += CTHR) lds_i[i] = P[c * NT + lo + i];
        __syncthreads();
        const int n_r = gcur[r];
        const int S = (n_r + CH - 1) / CH;  // identical chunking to P2
        const int s0 = c * S;
        int s1 = s0 + S; if (s1 > n_r) s1 = n_r;
        for (int v = s0 + tid; v < s1; v += CTHR) {
            const unsigned int w = (unsigned int)bkt[r * BCAP + v];
            const int pos = atomicAdd(&lds_i[w >> 18], 1);
            csr_src[pos] = (int)(w & 0x3FFFFu);
        }
    }
}

// ---------------- layer-1 GEMM with fused f32->bf16 staging (R7-proven) ----------------
__global__ __launch_bounds__(256) void gemmE_k(const float* __restrict__ emb_sr,
                                               const float* __restrict__ emb_tg,
                                               const unsigned short* __restrict__ Wt,
                                               const float* __restrict__ dinv,
                                               unsigned short* __restrict__ Gb) {
    __shared__ unsigned short xs[64 * PAD];   // 17.4 KB
    __shared__ unsigned short ws[128 * PAD];  // 34.8 KB
    const int tid = threadIdx.x;
    const int row0 = blockIdx.x * 64;         // NT % 64 == 0

    for (int i = tid; i < 128 * 16; i += 256) {
        const int r = i >> 4, o = i & 15;
        *(uint4*)&ws[r * PAD + o * 8] = *(const uint4*)&Wt[r * DIM + o * 8];
    }
    for (int i = tid; i < 64 * 32; i += 256) {  // 64 rows x 32 float4
        const int r = i >> 5, o = i & 31;
        const int gr = row0 + r;
        const float4 v = (gr < NN) ? ((const float4*)emb_sr)[gr * 32 + o]
                                   : ((const float4*)emb_tg)[(gr - NN) * 32 + o];
        ushort4 b;
        b.x = f2bf(v.x); b.y = f2bf(v.y); b.z = f2bf(v.z); b.w = f2bf(v.w);
        *(ushort4*)&xs[r * PAD + o * 4] = b;
    }
    __syncthreads();

    const int wave = tid >> 6;
    const int lane = tid & 63;
    const int m = lane & 15;
    const int quad = lane >> 4;
    const int rbase = wave * 16;

    frag_cd acc[8];
#pragma unroll
    for (int ct = 0; ct < 8; ct++) acc[ct] = (frag_cd){0.f, 0.f, 0.f, 0.f};

#pragma unroll
    for (int ks = 0; ks < 4; ks++) {
        const frag_ab a = *(const frag_ab*)&xs[(rbase + m) * PAD + ks * 32 + quad * 8];
#pragma unroll
        for (int ct = 0; ct < 8; ct++) {
            const frag_ab b = *(const frag_ab*)&ws[(ct * 16 + m) * PAD + ks * 32 + quad * 8];
            acc[ct] = __builtin_amdgcn_mfma_f32_16x16x32_bf16(a, b, acc[ct], 0, 0, 0);
        }
    }

    // C/D layout: col = lane&15, row = quad*4 + reg
#pragma unroll
    for (int r = 0; r < 4; r++) {
        const int grow = row0 + rbase + quad * 4 + r;
        const float dv = dinv[grow];
#pragma unroll
        for (int ct = 0; ct < 8; ct++)
            Gb[grow * DIM + ct * 16 + m] = f2bf(dv * acc[ct][r]);
    }
}

// ---------------- layer-2 GEMM (bf16 input), LDS-staged W (R7-proven) ----------------
__global__ __launch_bounds__(256) void gemm_mfma_k(const unsigned short* __restrict__ Xb,
                                                   const unsigned short* __restrict__ Wt,
                                                   const float* __restrict__ dinv,
                                                   unsigned short* __restrict__ Gb) {
    __shared__ unsigned short xs[64 * PAD];   // 17.4 KB
    __shared__ unsigned short ws[128 * PAD];  // 34.8 KB
    const int tid = threadIdx.x;
    const int row0 = blockIdx.x * 64;

    for (int i = tid; i < 128 * 16; i += 256) {
        const int r = i >> 4, o = i & 15;
        *(uint4*)&ws[r * PAD + o * 8] = *(const uint4*)&Wt[r * DIM + o * 8];
    }
    for (int i = tid; i < 64 * 16; i += 256) {
        const int r = i >> 4, o = i & 15;
        *(uint4*)&xs[r * PAD + o * 8] = *(const uint4*)&Xb[(row0 + r) * DIM + o * 8];
    }
    __syncthreads();

    const int wave = tid >> 6;
    const int lane = tid & 63;
    const int m = lane & 15;
    const int quad = lane >> 4;
    const int rbase = wave * 16;

    frag_cd acc[8];
#pragma unroll
    for (int ct = 0; ct < 8; ct++) acc[ct] = (frag_cd){0.f, 0.f, 0.f, 0.f};

#pragma unroll
    for (int ks = 0; ks < 4; ks++) {
        const frag_ab a = *(const frag_ab*)&xs[(rbase + m) * PAD + ks * 32 + quad * 8];
#pragma unroll
        for (int ct = 0; ct < 8; ct++) {
            const frag_ab b = *(const frag_ab*)&ws[(ct * 16 + m) * PAD + ks * 32 + quad * 8];
            acc[ct] = __builtin_amdgcn_mfma_f32_16x16x32_bf16(a, b, acc[ct], 0, 0, 0);
        }
    }

#pragma unroll
    for (int r = 0; r < 4; r++) {
        const int grow = row0 + rbase + quad * 4 + r;
        const float dv = dinv[grow];
#pragma unroll
        for (int ct = 0; ct < 8; ct++)
            Gb[grow * DIM + ct * 16 + m] = f2bf(dv * acc[ct][r]);
    }
}

// ---------------- fused pull (R10-proven) ----------------
// out[t] = relu( dinv[t]*(g[t] + Σ g[src]) + g[t]*sqrt(deg[t]) )
template <bool OUT_BF16>
__global__ __launch_bounds__(256) void pull_k(const int* __restrict__ row_ptr,
                                              const int* __restrict__ csr_src,
                                              const float* __restrict__ dinv,
                                              const unsigned short* __restrict__ Gb,
                                              float* __restrict__ outf,
                                              unsigned short* __restrict__ outb) {
    const int node = (blockIdx.x * 256 + threadIdx.x) >> 6;
    if (node >= NT) return;
    const int lane = threadIdx.x & 63;
    const unsigned int* __restrict__ G2 = (const unsigned int*)Gb;

    const int beg = row_ptr[node];
    const int end = row_ptr[node + 1];
    const float d = dinv[node];
    const float sq = 1.0f / d;  // sqrt(deg)

    const unsigned int gu = G2[node * 64 + lane];
    float sx = bflo(gu);  // self-loop term g[t]
    float sy = bfhi(gu);
    const float hx = sx * sq;  // residual h[t] = g[t]*sqrt(deg)
    const float hy = sy * sq;

    for (int base = beg; base < end; base += 64) {
        int rem = end - base; if (rem > 64) rem = 64;
        const int sl = (lane < rem)
            ? __builtin_nontemporal_load(&csr_src[base + lane]) : 0;
        int j = 0;
        for (; j + 16 <= rem; j += 16) {  // 16 outstanding gathers
            int ss[16];
            unsigned int mm[16];
#pragma unroll
            for (int q = 0; q < 16; ++q) ss[q] = __shfl(sl, j + q);
#pragma unroll
            for (int q = 0; q < 16; ++q) mm[q] = G2[ss[q] * 64 + lane];
#pragma unroll
            for (int q = 0; q < 16; ++q) { sx += bflo(mm[q]); sy += bfhi(mm[q]); }
        }
        for (; j + 8 <= rem; j += 8) {
            int ss[8];
            unsigned int mm[8];
#pragma unroll
            for (int q = 0; q < 8; ++q) ss[q] = __shfl(sl, j + q);
#pragma unroll
            for (int q = 0; q < 8; ++q) mm[q] = G2[ss[q] * 64 + lane];
#pragma unroll
            for (int q = 0; q < 8; ++q) { sx += bflo(mm[q]); sy += bfhi(mm[q]); }
        }
        for (; j + 4 <= rem; j += 4) {
            int ss[4];
            unsigned int mm[4];
#pragma unroll
            for (int q = 0; q < 4; ++q) ss[q] = __shfl(sl, j + q);
#pragma unroll
            for (int q = 0; q < 4; ++q) mm[q] = G2[ss[q] * 64 + lane];
#pragma unroll
            for (int q = 0; q < 4; ++q) { sx += bflo(mm[q]); sy += bfhi(mm[q]); }
        }
        for (; j < rem; ++j) {
            const int s = __shfl(sl, j);
            const unsigned int mu = G2[s * 64 + lane];
            sx += bflo(mu);
            sy += bfhi(mu);
        }
    }
    const float ax = fmaxf(d * sx + hx, 0.f);
    const float ay = fmaxf(d * sy + hy, 0.f);
    if (OUT_BF16) {
        const unsigned int o =
            (unsigned int)f2bf(ax) | ((unsigned int)f2bf(ay) << 16);
        __builtin_nontemporal_store(o, &((unsigned int*)outb)[node * 64 + lane]);
    } else {
        f32x2 o; o.x = ax; o.y = ay;
        __builtin_nontemporal_store(o, &((f32x2*)outf)[node * 64 + lane]);
    }
}

// ---------------- seed gather (both seed sets in one dispatch) ----------------
__global__ __launch_bounds__(256) void gather2_k(const int* __restrict__ sr_seeds,
                                                 const int* __restrict__ tg_seeds,
                                                 const float* __restrict__ ent,
                                                 float* __restrict__ sr_out,
                                                 float* __restrict__ tg_out) {
    const int gid = blockIdx.x * 256 + threadIdx.x;
    const int s = gid >> 5;
    if (s >= 2 * NS) return;
    const int q = gid & 31;
    const bool tg = s >= NS;
    const int si = tg ? s - NS : s;
    const int node = tg ? tg_seeds[si] + NN : sr_seeds[si];
    float* o = tg ? tg_out : sr_out;
    ((float4*)o)[si * 32 + q] = ((const float4*)ent)[node * 32 + q];
}

extern "C" void kernel_launch(void* const* d_in, const int* in_sizes, int n_in,
                              void* d_out, int out_size, void* d_ws, size_t ws_size,
                              hipStream_t stream) {
    const int* sr_seeds = (const int*)d_in[0];
    const int* tg_seeds = (const int*)d_in[1];
    const int* edges_sr = (const int*)d_in[2];
    const int* edges_tg = (const int*)d_in[3];
    const float* emb_sr = (const float*)d_in[4];
    const float* emb_tg = (const float*)d_in[5];
    const float* W0 = (const float*)d_in[6];
    const float* W1 = (const float*)d_in[7];
    float* out = (float*)d_out;

    // ws layout (4B words): cnt[200704] dinv[200704] row_ptr[200704]
    // bsum[1024] csr_src[ET] wt0+wt1[16384 words] hb[NT*DIM ushort]
    // total = 66.5 MB (R3-proven footprint, unchanged).
    // Inside hb: P[CH*NT]=3.2M then bkt[NRANGE*BCAP]=3.36M words — both dead
    // before gemmE writes hb.  gcur[16] in the unused tail of bsum.
    int* cnt = (int*)d_ws;
    float* dinv = (float*)(cnt + 200704);
    int* row_ptr = (int*)(dinv + 200704);
    int* bsum = row_ptr + 200704;
    int* csr_src = bsum + 1024;
    unsigned short* wt0 = (unsigned short*)(csr_src + ET);
    unsigned short* wt1 = wt0 + DIM * DIM;
    unsigned short* hb = wt1 + DIM * DIM;  // [NT*DIM] bf16 (g buffer)
    int* P = (int*)hb;                     // [CH][NT] ints
    int* bkt = P + CH * NT;                // [NRANGE*BCAP] packed edges
    int* gcur = bsum + 800;                // [16] bucket cursors

    // output layout (floats): sr_seed | tg_seed | ent [NT, DIM]
    // x1 (bf16) borrows the ent region: written by pull<true>, consumed by
    // layer-2 gemm before pull<false> overwrites the region with final f32.
    float* sr_seed_out = out;
    float* tg_seed_out = out + (long long)NS * DIM;
    float* ent = out + (long long)2 * NS * DIM;
    unsigned short* xb = (unsigned short*)ent;

    const int gGemm = (NT + 63) / 64;      // 3125
    const int gPull = NT / 4;              // 50000

    // ---- CSR build: one cooperative dispatch (was 6) ----
    hipMemsetAsync(gcur, 0, NRANGE * sizeof(int), stream);
    {
        void* args[] = {(void*)&W0, (void*)&W1, (void*)&wt0, (void*)&wt1,
                        (void*)&edges_sr, (void*)&edges_tg,
                        (void*)&gcur, (void*)&bkt, (void*)&P,
                        (void*)&cnt, (void*)&dinv, (void*)&bsum,
                        (void*)&row_ptr, (void*)&csr_src};
        hipLaunchCooperativeKernel((const void*)csr_coop_k, dim3(CGRID),
                                   dim3(CTHR), args, 0, stream);
    }

    // layer 1: g1 = dinv ⊙ (bf16(emb)@W0) -> hb
    gemmE_k<<<gGemm, 256, 0, stream>>>(emb_sr, emb_tg, wt0, dinv, hb);
    pull_k<true><<<gPull, 256, 0, stream>>>(row_ptr, csr_src, dinv, hb, nullptr, xb);
    // layer 2: g2 = dinv ⊙ (x1@W1) -> hb ; ent(f32) overwrites x1's region
    gemm_mfma_k<<<gGemm, 256, 0, stream>>>(xb, wt1, dinv, hb);
    pull_k<false><<<gPull, 256, 0, stream>>>(row_ptr, csr_src, dinv, hb, ent, nullptr);

    const int gSeed = (2 * NS * 32 + 255) / 256;
    gather2_k<<<gSeed, 256, 0, stream>>>(sr_seeds, tg_seeds, ent, sr_seed_out, tg_seed_out);
}